// Round 1
// baseline (1415.953 us; speedup 1.0000x reference)
//
#include <hip/hip_runtime.h>
#include <math.h>

// Problem constants
constexpr int B_  = 128;
constexpr int S_  = 256;
constexpr int D_  = 128;   // d_model
constexpr int H_  = 8;
constexpr int DK_ = 16;
constexpr int SK_ = 30;    // SAMPLE_K
constexpr int NT_ = 30;    // N_TOP
constexpr int KS_ = 7;     // conv kernel size

// ---------------------------------------------------------------------------
// K1: rotary for q and k.
//  q -> q_h in (B,H,S,DK) layout; k -> k_rot in (B,S,D) layout (conv input).
//  freqs/angles in double to stay within ~1e-7 of any fp32/fp64 reference
//  (top-k selection stability).
// ---------------------------------------------------------------------------
__global__ __launch_bounds__(256) void rotary_kernel(
    const float* __restrict__ q, const float* __restrict__ k,
    float* __restrict__ q_h, float* __restrict__ k_rot)
{
    int tid = blockIdx.x * 256 + threadIdx.x;   // over B*S*64, exact
    int f = tid & 63;
    int l = (tid >> 6) & 255;
    int b = tid >> 14;

    double freq = exp(((double)(-f) / 64.0) * 9.210340371976184); // ln(10000)
    double ang  = (double)l * freq;
    float c = (float)cos(ang);
    float s = (float)sin(ang);

    int base = (b * S_ + l) * D_ + 2 * f;
    float q0 = q[base], q1 = q[base + 1];
    float k0 = k[base], k1 = k[base + 1];

    float qr = q0 * c - q1 * s;
    float qi = q0 * s + q1 * c;
    float kr = k0 * c - k1 * s;
    float ki = k0 * s + k1 * c;

    // k in natural (B,S,D) layout for the conv
    k_rot[base]     = kr;
    k_rot[base + 1] = ki;

    // q in (B,H,S,DK) layout
    int d = 2 * f;
    int h = d >> 4, dk = d & 15;
    int qb = ((b * H_ + h) * S_ + l) * DK_ + dk;
    q_h[qb]     = qr;
    q_h[qb + 1] = qi;
}

// ---------------------------------------------------------------------------
// K2: causal conv along d with channels = seq (the dominant 7.5 GMAC matmul).
//  y[b,o,d] = sum_{i,t} w[o,i,t] * x[b,i,d+t-6]  + bias[o]
//  Output written directly in (B,H,S,DK) head layout (seq index = o).
//  Block: 128 threads (one per d). o-tile of 32 per block, grid (B, 8).
//  x staged in LDS in 64-row chunks with an 8-float zero left-pad per row
//  (causal boundary handled with no branches). w reads are wave-uniform ->
//  scalar loads. VALU-bound by design.
// ---------------------------------------------------------------------------
__global__ __launch_bounds__(128) void conv_kernel(
    const float* __restrict__ x, const float* __restrict__ w,
    const float* __restrict__ bias, float* __restrict__ yh)
{
    __shared__ float xs[64 * 136];   // 64 rows * (8 pad + 128 data) = 34.8 KB
    int b     = blockIdx.x;
    int obase = blockIdx.y * 32;
    int d     = threadIdx.x;         // 0..127

    float acc[32];
#pragma unroll
    for (int o = 0; o < 32; o++) acc[o] = 0.f;

    for (int ic = 0; ic < 4; ic++) {
        __syncthreads();
        // zero the 8-float left pads
        for (int p = d; p < 64 * 8; p += 128)
            xs[(p >> 3) * 136 + (p & 7)] = 0.f;
        // stage 64 rows of x[b] (float4, coalesced)
        const float4* src = (const float4*)(x + ((size_t)b * S_ + ic * 64) * D_);
        for (int idx = d; idx < 64 * 32; idx += 128) {
            int row = idx >> 5, c4 = idx & 31;
            *((float4*)(xs + row * 136 + 8) + c4) = src[row * 32 + c4];
        }
        __syncthreads();

        for (int il = 0; il < 64; il++) {
            int i = ic * 64 + il;
            float xv[7];
#pragma unroll
            for (int t = 0; t < 7; t++)
                xv[t] = xs[il * 136 + 2 + d + t];   // = x[b,i,d+t-6], zero-padded
            const float* wp = w + ((size_t)obase * S_ + i) * KS_;
#pragma unroll
            for (int o = 0; o < 32; o++) {
                const float* wr = wp + (size_t)o * S_ * KS_;  // uniform -> s_load
                float a = acc[o];
#pragma unroll
                for (int t = 0; t < 7; t++) a = fmaf(wr[t], xv[t], a);
                acc[o] = a;
            }
        }
    }

    int h = d >> 4, dk = d & 15;
#pragma unroll
    for (int o = 0; o < 32; o++) {
        int oc = obase + o;
        yh[(((size_t)b * H_ + h) * S_ + oc) * DK_ + dk] = acc[o] + bias[oc];
    }
}

// ---------------------------------------------------------------------------
// K3: sampled scores, M = max - mean, stable top-30 selection by rank count.
//  One block per (b,h). K tile in LDS padded to stride 17 (bank-conflict-free
//  for random j). Rank: #(M_j > M_l) + #(M_j == M_l && j < l) < 30 -> selected
//  (exactly matches jax.lax.top_k's stable tie-break; exactly 30 survive).
// ---------------------------------------------------------------------------
__global__ __launch_bounds__(256) void topk_kernel(
    const float* __restrict__ q_h, const float* __restrict__ k_h,
    const int* __restrict__ idxs, int* __restrict__ sel)
{
    __shared__ float ks[S_ * 17];
    __shared__ float Marr[S_];
    __shared__ int cnt;
    int bh  = blockIdx.x;
    int tid = threadIdx.x;
    if (tid == 0) cnt = 0;

    const float* kp = k_h + (size_t)bh * S_ * DK_;
    for (int idx = tid; idx < S_ * DK_; idx += 256)
        ks[(idx >> 4) * 17 + (idx & 15)] = kp[idx];
    __syncthreads();

    float qr[16];
    const float4* qp = (const float4*)(q_h + ((size_t)bh * S_ + tid) * DK_);
#pragma unroll
    for (int i = 0; i < 4; i++) {
        float4 t4 = qp[i];
        qr[4*i] = t4.x; qr[4*i+1] = t4.y; qr[4*i+2] = t4.z; qr[4*i+3] = t4.w;
    }

    float mx = -1e30f, sm = 0.f;
    for (int s = 0; s < SK_; s++) {
        int j = idxs[tid * SK_ + s];
        const float* kr = ks + j * 17;
        float dot = 0.f;
#pragma unroll
        for (int i = 0; i < 16; i++) dot = fmaf(qr[i], kr[i], dot);
        mx = fmaxf(mx, dot);
        sm += dot;
    }
    float M = mx - sm * (1.0f / 30.0f);
    Marr[tid] = M;
    __syncthreads();

    int higher = 0;
    for (int j = 0; j < S_; j++) {
        float Mj = Marr[j];
        if (Mj > M || (Mj == M && j < tid)) higher++;
    }
    if (higher < NT_) {
        int slot = atomicAdd(&cnt, 1);
        sel[bh * NT_ + slot] = tid;   // order irrelevant: scatter is by index
    }
}

// ---------------------------------------------------------------------------
// K4: attention over selected rows + context assembly.
//  One block per (b,h): stage K,V (stride-17 LDS), compute vmean, write the
//  vmean baseline for all 256 rows, then for each of the 30 selected rows:
//  scores over all 256 keys, block softmax, attn @ V, overwrite the ctx row.
//  ctx layout: (B,S,D) so the final linear reads rows contiguously.
// ---------------------------------------------------------------------------
__global__ __launch_bounds__(256) void attn_kernel(
    const float* __restrict__ q_h, const float* __restrict__ k_h,
    const float* __restrict__ v_h, const int* __restrict__ sel,
    float* __restrict__ ctx)
{
    __shared__ float ks[S_ * 17];
    __shared__ float vs[S_ * 17];
    __shared__ float qr[DK_];
    __shared__ float vmean_s[DK_];
    __shared__ float redm[4], reds[4];
    __shared__ float owave[4][DK_];

    int bh = blockIdx.x, b = bh >> 3, h = bh & 7;
    int tid  = threadIdx.x;
    int lane = tid & 63, wid = tid >> 6;

    const float* kp = k_h + (size_t)bh * S_ * DK_;
    const float* vp = v_h + (size_t)bh * S_ * DK_;
    for (int idx = tid; idx < S_ * DK_; idx += 256) {
        int r = idx >> 4, c = idx & 15;
        ks[r * 17 + c] = kp[idx];
        vs[r * 17 + c] = vp[idx];
    }
    __syncthreads();

    if (tid < DK_) {
        float s = 0.f;
        for (int j = 0; j < S_; j++) s += vs[j * 17 + tid];
        vmean_s[tid] = s * (1.0f / 256.0f);
    }
    __syncthreads();

    // baseline: every row gets vmean for this head
    {
        float* cp = ctx + ((size_t)(b * S_ + tid)) * D_ + h * DK_;
#pragma unroll
        for (int i = 0; i < 16; i++) cp[i] = vmean_s[i];
    }

    for (int u = 0; u < NT_; u++) {
        int l = sel[bh * NT_ + u];
        if (tid < DK_) qr[tid] = q_h[((size_t)bh * S_ + l) * DK_ + tid];
        __syncthreads();

        const float* kr = ks + tid * 17;
        float sc = 0.f;
#pragma unroll
        for (int i = 0; i < 16; i++) sc = fmaf(qr[i], kr[i], sc);
        sc *= 0.25f;   // 1/sqrt(16)

        float m = sc;
#pragma unroll
        for (int off = 32; off; off >>= 1) m = fmaxf(m, __shfl_xor(m, off));
        if (lane == 0) redm[wid] = m;
        __syncthreads();
        m = fmaxf(fmaxf(redm[0], redm[1]), fmaxf(redm[2], redm[3]));

        float e = expf(sc - m);
        float ssum = e;
#pragma unroll
        for (int off = 32; off; off >>= 1) ssum += __shfl_xor(ssum, off);
        if (lane == 0) reds[wid] = ssum;
        __syncthreads();
        ssum = (reds[0] + reds[1]) + (reds[2] + reds[3]);
        float attn = e / ssum;

        const float* vr = vs + tid * 17;
#pragma unroll
        for (int dk = 0; dk < 16; dk++) {
            float val = attn * vr[dk];
#pragma unroll
            for (int off = 32; off; off >>= 1) val += __shfl_xor(val, off);
            if (lane == 0) owave[wid][dk] = val;
        }
        __syncthreads();
        if (tid < DK_) {
            float o = (owave[0][tid] + owave[1][tid]) + (owave[2][tid] + owave[3][tid]);
            ctx[((size_t)(b * S_ + l)) * D_ + h * DK_ + tid] = o;
        }
        __syncthreads();
    }
}

// ---------------------------------------------------------------------------
// K5: final linear out = ctx @ w^T + b.
//  Each thread owns one output column e and keeps w[e][:] in 128 VGPRs.
//  ctx row elements are block-uniform -> scalar (s_load) broadcasts, so the
//  kernel is VALU-bound (no LDS in the inner loop). 256 blocks x 128 rows.
// ---------------------------------------------------------------------------
__global__ __launch_bounds__(256) void linear_kernel(
    const float* __restrict__ ctx, const float* __restrict__ w,
    const float* __restrict__ bias, float* __restrict__ out)
{
    int tid = threadIdx.x;
    int e  = tid & 127;
    int rg = tid >> 7;

    float wreg[128];
    const float4* wr4 = (const float4*)(w + (size_t)e * D_);
#pragma unroll
    for (int c4 = 0; c4 < 32; c4++) {
        float4 t4 = wr4[c4];
        wreg[4*c4] = t4.x; wreg[4*c4+1] = t4.y; wreg[4*c4+2] = t4.z; wreg[4*c4+3] = t4.w;
    }
    float be = bias[e];

    size_t rbase = (size_t)blockIdx.x * 128 + (size_t)rg * 64;
    for (int rl = 0; rl < 64; rl++) {
        const float* crow = ctx + (rbase + rl) * D_;   // uniform -> scalar loads
        float a0 = 0.f, a1 = 0.f, a2 = 0.f, a3 = 0.f;
#pragma unroll
        for (int c = 0; c < 128; c += 4) {
            a0 = fmaf(crow[c],     wreg[c],     a0);
            a1 = fmaf(crow[c + 1], wreg[c + 1], a1);
            a2 = fmaf(crow[c + 2], wreg[c + 2], a2);
            a3 = fmaf(crow[c + 3], wreg[c + 3], a3);
        }
        out[(rbase + rl) * D_ + e] = be + ((a0 + a1) + (a2 + a3));
    }
}

// ---------------------------------------------------------------------------
extern "C" void kernel_launch(void* const* d_in, const int* in_sizes, int n_in,
                              void* d_out, int out_size, void* d_ws, size_t ws_size,
                              hipStream_t stream)
{
    const float* query = (const float*)d_in[0];
    const float* key   = (const float*)d_in[1];
    const float* value = (const float*)d_in[2];
    const float* ckw   = (const float*)d_in[3];
    const float* ckb   = (const float*)d_in[4];
    const float* cvw   = (const float*)d_in[5];
    const float* cvb   = (const float*)d_in[6];
    const float* lw    = (const float*)d_in[7];
    const float* lb    = (const float*)d_in[8];
    const int*   isamp = (const int*)d_in[9];
    float* out = (float*)d_out;
    float* ws  = (float*)d_ws;

    const size_t NBSD = (size_t)B_ * S_ * D_;   // 4,194,304 floats
    float* q_h  = ws;                 // (B,H,S,DK)
    float* kbuf = ws + NBSD;          // k_rot (B,S,D); reused as ctx after conv
    float* k_h  = ws + 2 * NBSD;      // (B,H,S,DK)
    float* v_h  = ws + 3 * NBSD;      // (B,H,S,DK)
    int*   sel  = (int*)(ws + 4 * NBSD);   // (B*H, 30)

    rotary_kernel<<<dim3((B_ * S_ * 64) / 256), 256, 0, stream>>>(query, key, q_h, kbuf);
    conv_kernel<<<dim3(B_, 8), 128, 0, stream>>>(kbuf,  ckw, ckb, k_h);
    conv_kernel<<<dim3(B_, 8), 128, 0, stream>>>(value, cvw, cvb, v_h);
    topk_kernel<<<dim3(B_ * H_), 256, 0, stream>>>(q_h, k_h, isamp, sel);
    attn_kernel<<<dim3(B_ * H_), 256, 0, stream>>>(q_h, k_h, v_h, sel, kbuf);
    linear_kernel<<<dim3(256), 256, 0, stream>>>(kbuf, lw, lb, out);
}

// Round 2
// 354.828 us; speedup vs baseline: 3.9905x; 3.9905x over previous
//
#include <hip/hip_runtime.h>
#include <math.h>

// Problem constants
constexpr int B_  = 128;
constexpr int S_  = 256;
constexpr int D_  = 128;   // d_model
constexpr int H_  = 8;
constexpr int DK_ = 16;
constexpr int SK_ = 30;    // SAMPLE_K
constexpr int NT_ = 30;    // N_TOP

typedef short short8  __attribute__((ext_vector_type(8)));
typedef float floatx4 __attribute__((ext_vector_type(4)));

__device__ inline ushort bf16_rne(float f) {
    unsigned u = __float_as_uint(f);
    u += 0x7fffu + ((u >> 16) & 1u);
    return (ushort)(u >> 16);
}
__device__ inline float bf16_to_f(ushort h) {
    return __uint_as_float(((unsigned)h) << 16);
}

// ---------------------------------------------------------------------------
// K0: W prep — transpose conv weights (o,i,t) fp32 -> [t][o][i] bf16 hi/lo.
//  Batch-independent; i-contiguous so MFMA B-frag loads are 16B dwordx4.
//  k-conv needs hi+lo (top-k precision); v-conv hi only.
// ---------------------------------------------------------------------------
__global__ __launch_bounds__(256) void wprep_kernel(
    const float* __restrict__ wk, const float* __restrict__ wv,
    ushort* __restrict__ wk_hi, ushort* __restrict__ wk_lo,
    ushort* __restrict__ wv_hi)
{
    int tid = blockIdx.x * 256 + threadIdx.x;   // 0 .. 131071
    int which = tid >> 16;                      // 0 = k-conv, 1 = v-conv
    int oi = tid & 65535;                       // o*256 + i
    const float* src = (which ? wv : wk) + (size_t)oi * 7;
#pragma unroll
    for (int t = 0; t < 7; t++) {
        float f = src[t];
        ushort hi = bf16_rne(f);
        size_t dst = (size_t)t * 65536 + oi;
        if (which) {
            wv_hi[dst] = hi;
        } else {
            wk_hi[dst] = hi;
            wk_lo[dst] = bf16_rne(f - bf16_to_f(hi));
        }
    }
}

// ---------------------------------------------------------------------------
// K1: rotary (double-precision angles for top-k selection stability).
// ---------------------------------------------------------------------------
__global__ __launch_bounds__(256) void rotary_kernel(
    const float* __restrict__ q, const float* __restrict__ k,
    float* __restrict__ q_h, float* __restrict__ k_rot)
{
    int tid = blockIdx.x * 256 + threadIdx.x;   // over B*S*64
    int f = tid & 63;
    int l = (tid >> 6) & 255;
    int b = tid >> 14;

    double freq = exp(((double)(-f) / 64.0) * 9.210340371976184); // ln(10000)
    double ang  = (double)l * freq;
    float c = (float)cos(ang);
    float s = (float)sin(ang);

    int base = (b * S_ + l) * D_ + 2 * f;
    float q0 = q[base], q1 = q[base + 1];
    float k0 = k[base], k1 = k[base + 1];

    float qr = q0 * c - q1 * s;
    float qi = q0 * s + q1 * c;
    float kr = k0 * c - k1 * s;
    float ki = k0 * s + k1 * c;

    k_rot[base]     = kr;     // (B,S,D) natural layout for conv input
    k_rot[base + 1] = ki;

    int d = 2 * f;
    int h = d >> 4, dk = d & 15;
    int qb = ((b * H_ + h) * S_ + l) * DK_ + dk;
    q_h[qb]     = qr;         // (B,H,S,DK)
    q_h[qb + 1] = qi;
}

// ---------------------------------------------------------------------------
// K2: causal-conv-as-MFMA-GEMM.  Y[o,d] = sum_{i,t} W[o,i,t] * X[i, d+t-6].
//  Operand-swapped 16x16x32 bf16 MFMA: A = X (LDS, c = d+6 padded layout,
//  stride 72 = 16B-aligned, 2-way banks = free), B = W ([t][o][i] global,
//  L2-resident).  Block = 64o x 128d, 4 waves as 2x2 (wave = 32o x 64d):
//  per t-step 8 ds_read_b128 + 4 global 16B -> 24 MFMAs (KP) / 8 (v).
//  KP=true: 3-product hi/lo split (fp32-equivalent, protects top-k);
//  KP=false: single hi*hi product (v path, error ~2e-3 at output).
// ---------------------------------------------------------------------------
template<bool KP>
__global__ __launch_bounds__(256) void conv_mfma_kernel(
    const float* __restrict__ x, const ushort* __restrict__ whi,
    const ushort* __restrict__ wlo, const float* __restrict__ bias,
    float* __restrict__ yh)
{
    constexpr int LI = 72;                    // 64 i + 8 pad (16B-aligned rows)
    __shared__ ushort xhi[134 * LI];
    __shared__ ushort xlo[KP ? 134 * LI : 8];

    int b    = blockIdx.x;
    int oblk = blockIdx.y * 64;
    int tid  = threadIdx.x;
    int lane = tid & 63, wid = tid >> 6;
    int lm = lane & 15, kb = lane >> 4;
    int ow = wid >> 1, dw = wid & 1;
    int obase = oblk + ow * 32;
    int dbase = dw * 64;

    floatx4 acc[8];
#pragma unroll
    for (int i = 0; i < 8; i++) acc[i] = (floatx4){0.f, 0.f, 0.f, 0.f};

    // zero the causal left pad (c < 6), written once, never overwritten
    for (int idx = tid; idx < 6 * LI; idx += 256) {
        xhi[idx] = 0;
        if (KP) xlo[idx] = 0;
    }

    const ushort* abase_h = xhi + (dbase + lm) * LI + kb * 8;
    const ushort* abase_l = KP ? (xlo + (dbase + lm) * LI + kb * 8) : (const ushort*)0;

    for (int ic = 0; ic < 4; ic++) {
        __syncthreads();
        {   // stage 64 i-rows: thread = (row i = tid&63, d-range g*32..g*32+32)
            int i = tid & 63, g = tid >> 6;
            const float4* src = (const float4*)(x + (((size_t)b * 256) + ic * 64 + i) * 128 + g * 32);
            ushort* dh = xhi + (g * 32 + 6) * LI + i;   // lane-consecutive i -> conflict-free
            ushort* dl = KP ? (xlo + (g * 32 + 6) * LI + i) : (ushort*)0;
#pragma unroll
            for (int q8 = 0; q8 < 8; q8++) {
                float4 v4 = src[q8];
                float vv[4] = {v4.x, v4.y, v4.z, v4.w};
#pragma unroll
                for (int cc = 0; cc < 4; cc++) {
                    ushort hb = bf16_rne(vv[cc]);
                    dh[(q8 * 4 + cc) * LI] = hb;
                    if (KP) dl[(q8 * 4 + cc) * LI] = bf16_rne(vv[cc] - bf16_to_f(hb));
                }
            }
        }
        __syncthreads();
#pragma unroll
        for (int ks2 = 0; ks2 < 2; ks2++) {
            int ibase = ic * 64 + ks2 * 32 + kb * 8;
#pragma unroll
            for (int t = 0; t < 7; t++) {
                short8 xh[4], xl[4];
#pragma unroll
                for (int nd = 0; nd < 4; nd++) {
                    xh[nd] = *(const short8*)(abase_h + (nd * 16 + t) * LI + ks2 * 32);
                    if (KP) xl[nd] = *(const short8*)(abase_l + (nd * 16 + t) * LI + ks2 * 32);
                }
                short8 wh[2], wl[2];
#pragma unroll
                for (int po = 0; po < 2; po++) {
                    int o = obase + po * 16 + lm;
                    wh[po] = *(const short8*)(whi + (size_t)t * 65536 + o * 256 + ibase);
                    if (KP) wl[po] = *(const short8*)(wlo + (size_t)t * 65536 + o * 256 + ibase);
                }
#pragma unroll
                for (int po = 0; po < 2; po++) {
#pragma unroll
                    for (int nd = 0; nd < 4; nd++) {
                        int a = po * 4 + nd;
                        acc[a] = __builtin_amdgcn_mfma_f32_16x16x32_bf16(xh[nd], wh[po], acc[a], 0, 0, 0);
                        if (KP) {
                            acc[a] = __builtin_amdgcn_mfma_f32_16x16x32_bf16(xl[nd], wh[po], acc[a], 0, 0, 0);
                            acc[a] = __builtin_amdgcn_mfma_f32_16x16x32_bf16(xh[nd], wl[po], acc[a], 0, 0, 0);
                        }
                    }
                }
            }
        }
    }

    // epilogue: D[m=d][n=o]; row = kb*4+r -> d-local, col = lm -> o-local
#pragma unroll
    for (int po = 0; po < 2; po++) {
        int o = obase + po * 16 + lm;
        float bv = bias[o];
#pragma unroll
        for (int nd = 0; nd < 4; nd++) {
            int dhi = dw * 4 + nd;   // d>>4
#pragma unroll
            for (int r = 0; r < 4; r++) {
                int dk = kb * 4 + r;
                yh[(((size_t)b * 8 + dhi) * 256 + o) * 16 + dk] = acc[po * 4 + nd][r] + bv;
            }
        }
    }
}

// ---------------------------------------------------------------------------
// K3: sampled scores, M = max - mean, stable top-30 by rank count.
//  Stride-20 LDS rows (16B-aligned) -> b128 K reads; q and sample indices in
//  registers.
// ---------------------------------------------------------------------------
__global__ __launch_bounds__(256) void topk_kernel(
    const float* __restrict__ q_h, const float* __restrict__ k_h,
    const int* __restrict__ idxs, int* __restrict__ sel)
{
    __shared__ float ks[S_ * 20];
    __shared__ float Marr[S_];
    __shared__ int cnt;
    int bh  = blockIdx.x;
    int tid = threadIdx.x;
    if (tid == 0) cnt = 0;

    const float* kp = k_h + (size_t)bh * S_ * DK_;
    for (int idx = tid; idx < S_ * DK_; idx += 256)
        ks[(idx >> 4) * 20 + (idx & 15)] = kp[idx];
    __syncthreads();

    float qr[16];
    const float4* qp = (const float4*)(q_h + ((size_t)bh * S_ + tid) * DK_);
#pragma unroll
    for (int i = 0; i < 4; i++) {
        float4 t4 = qp[i];
        qr[4*i] = t4.x; qr[4*i+1] = t4.y; qr[4*i+2] = t4.z; qr[4*i+3] = t4.w;
    }
    int idxr[SK_];
    const int* ip = idxs + tid * SK_;
#pragma unroll
    for (int s = 0; s < SK_; s++) idxr[s] = ip[s];

    float mx = -1e30f, sm = 0.f;
#pragma unroll
    for (int s = 0; s < SK_; s++) {
        const float4* kr = (const float4*)(ks + idxr[s] * 20);
        float4 k0 = kr[0], k1 = kr[1], k2 = kr[2], k3 = kr[3];
        float d0 = qr[0]*k0.x, d1 = qr[1]*k0.y, d2 = qr[2]*k0.z, d3 = qr[3]*k0.w;
        d0 = fmaf(qr[4],  k1.x, d0); d1 = fmaf(qr[5],  k1.y, d1);
        d2 = fmaf(qr[6],  k1.z, d2); d3 = fmaf(qr[7],  k1.w, d3);
        d0 = fmaf(qr[8],  k2.x, d0); d1 = fmaf(qr[9],  k2.y, d1);
        d2 = fmaf(qr[10], k2.z, d2); d3 = fmaf(qr[11], k2.w, d3);
        d0 = fmaf(qr[12], k3.x, d0); d1 = fmaf(qr[13], k3.y, d1);
        d2 = fmaf(qr[14], k3.z, d2); d3 = fmaf(qr[15], k3.w, d3);
        float dot = (d0 + d1) + (d2 + d3);
        mx = fmaxf(mx, dot);
        sm += dot;
    }
    float M = mx - sm * (1.0f / 30.0f);
    Marr[tid] = M;
    __syncthreads();

    int higher = 0;
    for (int j = 0; j < S_; j++) {
        float Mj = Marr[j];
        if (Mj > M || (Mj == M && j < tid)) higher++;
    }
    if (higher < NT_) {
        int slot = atomicAdd(&cnt, 1);
        sel[bh * NT_ + slot] = tid;   // order irrelevant: scatter is by index
    }
}

// ---------------------------------------------------------------------------
// K4: attention over selected rows + context assembly — all 30 rows in
//  parallel (group of 8 threads per selected row), no serial u-loop.
//  Baseline vmean rows and attn rows are disjoint (selflag), no write race.
// ---------------------------------------------------------------------------
__global__ __launch_bounds__(256) void attn_kernel(
    const float* __restrict__ q_h, const float* __restrict__ k_h,
    const float* __restrict__ v_h, const int* __restrict__ sel,
    float* __restrict__ ctx)
{
    __shared__ float ks[S_ * 20];
    __shared__ float vs[S_ * 20];
    __shared__ float P[NT_][S_ + 1];
    __shared__ float qs[NT_][16];
    __shared__ float partial[16][17];
    __shared__ float vmean_s[16];
    __shared__ int sel_s[NT_];
    __shared__ int selflag[S_];

    int bh = blockIdx.x, b = bh >> 3, h = bh & 7;
    int tid = threadIdx.x;

    const float* kp = k_h + (size_t)bh * S_ * DK_;
    const float* vp = v_h + (size_t)bh * S_ * DK_;
    for (int idx = tid; idx < S_ * DK_; idx += 256) {
        int r = idx >> 4, c = idx & 15;
        ks[r * 20 + c] = kp[idx];
        vs[r * 20 + c] = vp[idx];
    }
    selflag[tid] = 0;
    if (tid < NT_) sel_s[tid] = sel[bh * NT_ + tid];
    __syncthreads();
    if (tid < NT_) selflag[sel_s[tid]] = 1;
    for (int idx = tid; idx < NT_ * 16; idx += 256) {
        int u = idx >> 4, c = idx & 15;
        qs[u][c] = q_h[((size_t)bh * S_ + sel_s[u]) * DK_ + c];
    }
    {   // vmean: 16 chunks x 16 dk
        int dk = tid & 15, chunk = tid >> 4;
        float s = 0.f;
#pragma unroll
        for (int r = 0; r < 16; r++) s += vs[(chunk * 16 + r) * 20 + dk];
        partial[chunk][dk] = s;
    }
    __syncthreads();
    if (tid < 16) {
        float s = 0.f;
#pragma unroll
        for (int c = 0; c < 16; c++) s += partial[c][tid];
        vmean_s[tid] = s * (1.0f / 256.0f);
    }
    __syncthreads();

    // baseline rows (non-selected only -> no race with attn writes)
    if (!selflag[tid]) {
        float4* cp = (float4*)(ctx + ((size_t)(b * S_ + tid)) * D_ + h * DK_);
#pragma unroll
        for (int i = 0; i < 4; i++)
            cp[i] = make_float4(vmean_s[4*i], vmean_s[4*i+1],
                                vmean_s[4*i+2], vmean_s[4*i+3]);
    }

    // scores + softmax + PV: group g (8 threads) owns selected row g
    int g = tid >> 3, j = tid & 7;
    if (g < NT_) {
        float qreg[16];
        const float4* q4 = (const float4*)qs[g];
#pragma unroll
        for (int i = 0; i < 4; i++) {
            float4 t4 = q4[i];
            qreg[4*i] = t4.x; qreg[4*i+1] = t4.y; qreg[4*i+2] = t4.z; qreg[4*i+3] = t4.w;
        }
        float sc[32];
        float mx = -1e30f;
#pragma unroll
        for (int li = 0; li < 32; li++) {
            int l = j + li * 8;
            const float4* kr = (const float4*)(ks + l * 20);
            float4 k0 = kr[0], k1 = kr[1], k2 = kr[2], k3 = kr[3];
            float d0 = qreg[0]*k0.x, d1 = qreg[1]*k0.y, d2 = qreg[2]*k0.z, d3 = qreg[3]*k0.w;
            d0 = fmaf(qreg[4],  k1.x, d0); d1 = fmaf(qreg[5],  k1.y, d1);
            d2 = fmaf(qreg[6],  k1.z, d2); d3 = fmaf(qreg[7],  k1.w, d3);
            d0 = fmaf(qreg[8],  k2.x, d0); d1 = fmaf(qreg[9],  k2.y, d1);
            d2 = fmaf(qreg[10], k2.z, d2); d3 = fmaf(qreg[11], k2.w, d3);
            d0 = fmaf(qreg[12], k3.x, d0); d1 = fmaf(qreg[13], k3.y, d1);
            d2 = fmaf(qreg[14], k3.z, d2); d3 = fmaf(qreg[15], k3.w, d3);
            sc[li] = ((d0 + d1) + (d2 + d3)) * 0.25f;   // 1/sqrt(16)
            mx = fmaxf(mx, sc[li]);
        }
        mx = fmaxf(mx, __shfl_xor(mx, 1));
        mx = fmaxf(mx, __shfl_xor(mx, 2));
        mx = fmaxf(mx, __shfl_xor(mx, 4));
        float se = 0.f;
#pragma unroll
        for (int li = 0; li < 32; li++) {
            float e = __expf(sc[li] - mx);
            P[g][j + li * 8] = e;
            se += e;
        }
        se += __shfl_xor(se, 1);
        se += __shfl_xor(se, 2);
        se += __shfl_xor(se, 4);
        float inv = 1.0f / se;

        int dk0 = j * 2;
        float o0 = 0.f, o1 = 0.f;
#pragma unroll 8
        for (int l = 0; l < S_; l++) {
            float p = P[g][l];                          // same-wave writes, broadcast read
            float2 vv = *(const float2*)(vs + l * 20 + dk0);
            o0 = fmaf(p, vv.x, o0);
            o1 = fmaf(p, vv.y, o1);
        }
        int lrow = sel_s[g];
        float2* op = (float2*)(ctx + ((size_t)(b * S_ + lrow)) * D_ + h * DK_ + dk0);
        *op = make_float2(o0 * inv, o1 * inv);
    }
}

// ---------------------------------------------------------------------------
// K5: final linear out = ctx @ w^T + b.  w-row in 128 VGPRs per thread;
//  ctx rows via uniform scalar loads.  512 blocks -> 2 blocks/CU.
// ---------------------------------------------------------------------------
__global__ __launch_bounds__(256) void linear_kernel(
    const float* __restrict__ ctx, const float* __restrict__ w,
    const float* __restrict__ bias, float* __restrict__ out)
{
    int tid = threadIdx.x;
    int e  = tid & 127;
    int rg = tid >> 7;

    float wreg[128];
    const float4* wr4 = (const float4*)(w + (size_t)e * D_);
#pragma unroll
    for (int c4 = 0; c4 < 32; c4++) {
        float4 t4 = wr4[c4];
        wreg[4*c4] = t4.x; wreg[4*c4+1] = t4.y; wreg[4*c4+2] = t4.z; wreg[4*c4+3] = t4.w;
    }
    float be = bias[e];

    size_t rbase = (size_t)blockIdx.x * 64 + (size_t)rg * 32;
    for (int rl = 0; rl < 32; rl++) {
        const float* crow = ctx + (rbase + rl) * D_;   // uniform -> scalar loads
        float a0 = 0.f, a1 = 0.f, a2 = 0.f, a3 = 0.f;
#pragma unroll
        for (int c = 0; c < 128; c += 4) {
            a0 = fmaf(crow[c],     wreg[c],     a0);
            a1 = fmaf(crow[c + 1], wreg[c + 1], a1);
            a2 = fmaf(crow[c + 2], wreg[c + 2], a2);
            a3 = fmaf(crow[c + 3], wreg[c + 3], a3);
        }
        out[(rbase + rl) * D_ + e] = be + ((a0 + a1) + (a2 + a3));
    }
}

// ---------------------------------------------------------------------------
extern "C" void kernel_launch(void* const* d_in, const int* in_sizes, int n_in,
                              void* d_out, int out_size, void* d_ws, size_t ws_size,
                              hipStream_t stream)
{
    const float* query = (const float*)d_in[0];
    const float* key   = (const float*)d_in[1];
    const float* value = (const float*)d_in[2];
    const float* ckw   = (const float*)d_in[3];
    const float* ckb   = (const float*)d_in[4];
    const float* cvw   = (const float*)d_in[5];
    const float* cvb   = (const float*)d_in[6];
    const float* lw    = (const float*)d_in[7];
    const float* lb    = (const float*)d_in[8];
    const int*   isamp = (const int*)d_in[9];
    float* out = (float*)d_out;
    float* ws  = (float*)d_ws;

    const size_t NBSD = (size_t)B_ * S_ * D_;   // 4,194,304 floats
    float* q_h  = ws;                   // (B,H,S,DK)
    float* kbuf = ws + NBSD;            // k_rot (B,S,D); reused as ctx later
    float* k_h  = ws + 2 * NBSD;        // (B,H,S,DK)
    float* v_h  = ws + 3 * NBSD;        // (B,H,S,DK)
    int*   sel  = (int*)(ws + 4 * NBSD);        // (B*H, 30)
    ushort* wk_hi = (ushort*)(sel + B_ * H_ * NT_);   // [7][256][256] bf16 each
    ushort* wk_lo = wk_hi + 7 * 256 * 256;
    ushort* wv_hi = wk_lo + 7 * 256 * 256;

    wprep_kernel<<<dim3(512), 256, 0, stream>>>(ckw, cvw, wk_hi, wk_lo, wv_hi);
    rotary_kernel<<<dim3((B_ * S_ * 64) / 256), 256, 0, stream>>>(query, key, q_h, kbuf);
    conv_mfma_kernel<true ><<<dim3(B_, 4), 256, 0, stream>>>(kbuf,  wk_hi, wk_lo, ckb, k_h);
    conv_mfma_kernel<false><<<dim3(B_, 4), 256, 0, stream>>>(value, wv_hi, wv_hi, cvb, v_h);
    topk_kernel<<<dim3(B_ * H_), 256, 0, stream>>>(q_h, k_h, isamp, sel);
    attn_kernel<<<dim3(B_ * H_), 256, 0, stream>>>(q_h, k_h, v_h, sel, kbuf);
    linear_kernel<<<dim3(512), 256, 0, stream>>>(kbuf, lw, lb, out);
}

// Round 3
// 285.340 us; speedup vs baseline: 4.9623x; 1.2435x over previous
//
#include <hip/hip_runtime.h>
#include <math.h>

// Problem constants
constexpr int B_  = 128;
constexpr int S_  = 256;
constexpr int D_  = 128;   // d_model
constexpr int H_  = 8;
constexpr int DK_ = 16;
constexpr int SK_ = 30;    // SAMPLE_K
constexpr int NT_ = 30;    // N_TOP

typedef short short8  __attribute__((ext_vector_type(8)));
typedef float floatx4 __attribute__((ext_vector_type(4)));

__device__ inline ushort bf16_rne(float f) {
    unsigned u = __float_as_uint(f);
    u += 0x7fffu + ((u >> 16) & 1u);
    return (ushort)(u >> 16);
}
__device__ inline float bf16_to_f(ushort h) {
    return __uint_as_float(((unsigned)h) << 16);
}

// ---------------------------------------------------------------------------
// K0: W prep — conv weights (o,i,t) fp32 -> [t][o][i] bf16 hi/lo, plus
//  lin_w (e,c) fp32 -> bf16 hi/lo (natural layout).
// ---------------------------------------------------------------------------
__global__ __launch_bounds__(256) void wprep_kernel(
    const float* __restrict__ wk, const float* __restrict__ wv,
    const float* __restrict__ lw,
    ushort* __restrict__ wk_hi, ushort* __restrict__ wk_lo,
    ushort* __restrict__ wv_hi,
    ushort* __restrict__ lw_hi, ushort* __restrict__ lw_lo)
{
    int tid = blockIdx.x * 256 + threadIdx.x;   // 0 .. 147455
    if (tid < 131072) {
        int which = tid >> 16;                  // 0 = k-conv, 1 = v-conv
        int oi = tid & 65535;                   // o*256 + i
        const float* src = (which ? wv : wk) + (size_t)oi * 7;
#pragma unroll
        for (int t = 0; t < 7; t++) {
            float f = src[t];
            ushort hi = bf16_rne(f);
            size_t dst = (size_t)t * 65536 + oi;
            if (which) {
                wv_hi[dst] = hi;
            } else {
                wk_hi[dst] = hi;
                wk_lo[dst] = bf16_rne(f - bf16_to_f(hi));
            }
        }
    } else {
        int ec = tid - 131072;                  // e*128 + c, 16384 elements
        float f = lw[ec];
        ushort hi = bf16_rne(f);
        lw_hi[ec] = hi;
        lw_lo[ec] = bf16_rne(f - bf16_to_f(hi));
    }
}

// ---------------------------------------------------------------------------
// K0b: rotary trig table (double precision, computed once per launch).
//  tab[(l*64+f)*2] = cos, +1 = sin.  Bit-identical to the previous in-rotary
//  computation -> top-k selection unchanged.
// ---------------------------------------------------------------------------
__global__ __launch_bounds__(256) void trig_kernel(float* __restrict__ tab)
{
    int tid = blockIdx.x * 256 + threadIdx.x;   // 0 .. 16383
    int f = tid & 63, l = tid >> 6;
    double freq = exp(((double)(-f) / 64.0) * 9.210340371976184); // ln(10000)
    double ang  = (double)l * freq;
    tab[tid * 2]     = (float)cos(ang);
    tab[tid * 2 + 1] = (float)sin(ang);
}

// ---------------------------------------------------------------------------
// K1: rotary — table lookup, pure memory-bound.
// ---------------------------------------------------------------------------
__global__ __launch_bounds__(256) void rotary_kernel(
    const float* __restrict__ q, const float* __restrict__ k,
    const float* __restrict__ tab,
    float* __restrict__ q_h, float* __restrict__ k_rot)
{
    int tid = blockIdx.x * 256 + threadIdx.x;   // over B*S*64
    int f = tid & 63;
    int l = (tid >> 6) & 255;
    int b = tid >> 14;

    float2 cs = *(const float2*)(tab + (size_t)(l * 64 + f) * 2);
    float c = cs.x, s = cs.y;

    int base = (b * S_ + l) * D_ + 2 * f;
    float q0 = q[base], q1 = q[base + 1];
    float k0 = k[base], k1 = k[base + 1];

    float qr = q0 * c - q1 * s;
    float qi = q0 * s + q1 * c;
    float kr = k0 * c - k1 * s;
    float ki = k0 * s + k1 * c;

    k_rot[base]     = kr;     // (B,S,D) natural layout for conv input
    k_rot[base + 1] = ki;

    int d = 2 * f;
    int h = d >> 4, dk = d & 15;
    int qb = ((b * H_ + h) * S_ + l) * DK_ + dk;
    q_h[qb]     = qr;         // (B,H,S,DK)
    q_h[qb + 1] = qi;
}

// ---------------------------------------------------------------------------
// K2: causal-conv-as-MFMA-GEMM (unchanged from R2, passing).
// ---------------------------------------------------------------------------
template<bool KP>
__global__ __launch_bounds__(256) void conv_mfma_kernel(
    const float* __restrict__ x, const ushort* __restrict__ whi,
    const ushort* __restrict__ wlo, const float* __restrict__ bias,
    float* __restrict__ yh)
{
    constexpr int LI = 72;                    // 64 i + 8 pad (16B-aligned rows)
    __shared__ ushort xhi[134 * LI];
    __shared__ ushort xlo[KP ? 134 * LI : 8];

    int b    = blockIdx.x;
    int oblk = blockIdx.y * 64;
    int tid  = threadIdx.x;
    int lane = tid & 63, wid = tid >> 6;
    int lm = lane & 15, kb = lane >> 4;
    int ow = wid >> 1, dw = wid & 1;
    int obase = oblk + ow * 32;
    int dbase = dw * 64;

    floatx4 acc[8];
#pragma unroll
    for (int i = 0; i < 8; i++) acc[i] = (floatx4){0.f, 0.f, 0.f, 0.f};

    for (int idx = tid; idx < 6 * LI; idx += 256) {
        xhi[idx] = 0;
        if (KP) xlo[idx] = 0;
    }

    const ushort* abase_h = xhi + (dbase + lm) * LI + kb * 8;
    const ushort* abase_l = KP ? (xlo + (dbase + lm) * LI + kb * 8) : (const ushort*)0;

    for (int ic = 0; ic < 4; ic++) {
        __syncthreads();
        {
            int i = tid & 63, g = tid >> 6;
            const float4* src = (const float4*)(x + (((size_t)b * 256) + ic * 64 + i) * 128 + g * 32);
            ushort* dh = xhi + (g * 32 + 6) * LI + i;
            ushort* dl = KP ? (xlo + (g * 32 + 6) * LI + i) : (ushort*)0;
#pragma unroll
            for (int q8 = 0; q8 < 8; q8++) {
                float4 v4 = src[q8];
                float vv[4] = {v4.x, v4.y, v4.z, v4.w};
#pragma unroll
                for (int cc = 0; cc < 4; cc++) {
                    ushort hb = bf16_rne(vv[cc]);
                    dh[(q8 * 4 + cc) * LI] = hb;
                    if (KP) dl[(q8 * 4 + cc) * LI] = bf16_rne(vv[cc] - bf16_to_f(hb));
                }
            }
        }
        __syncthreads();
#pragma unroll
        for (int ks2 = 0; ks2 < 2; ks2++) {
            int ibase = ic * 64 + ks2 * 32 + kb * 8;
#pragma unroll
            for (int t = 0; t < 7; t++) {
                short8 xh[4], xl[4];
#pragma unroll
                for (int nd = 0; nd < 4; nd++) {
                    xh[nd] = *(const short8*)(abase_h + (nd * 16 + t) * LI + ks2 * 32);
                    if (KP) xl[nd] = *(const short8*)(abase_l + (nd * 16 + t) * LI + ks2 * 32);
                }
                short8 wh[2], wl[2];
#pragma unroll
                for (int po = 0; po < 2; po++) {
                    int o = obase + po * 16 + lm;
                    wh[po] = *(const short8*)(whi + (size_t)t * 65536 + o * 256 + ibase);
                    if (KP) wl[po] = *(const short8*)(wlo + (size_t)t * 65536 + o * 256 + ibase);
                }
#pragma unroll
                for (int po = 0; po < 2; po++) {
#pragma unroll
                    for (int nd = 0; nd < 4; nd++) {
                        int a = po * 4 + nd;
                        acc[a] = __builtin_amdgcn_mfma_f32_16x16x32_bf16(xh[nd], wh[po], acc[a], 0, 0, 0);
                        if (KP) {
                            acc[a] = __builtin_amdgcn_mfma_f32_16x16x32_bf16(xl[nd], wh[po], acc[a], 0, 0, 0);
                            acc[a] = __builtin_amdgcn_mfma_f32_16x16x32_bf16(xh[nd], wl[po], acc[a], 0, 0, 0);
                        }
                    }
                }
            }
        }
    }

#pragma unroll
    for (int po = 0; po < 2; po++) {
        int o = obase + po * 16 + lm;
        float bv = bias[o];
#pragma unroll
        for (int nd = 0; nd < 4; nd++) {
            int dhi = dw * 4 + nd;   // d>>4
#pragma unroll
            for (int r = 0; r < 4; r++) {
                int dk = kb * 4 + r;
                yh[(((size_t)b * 8 + dhi) * 256 + o) * 16 + dk] = acc[po * 4 + nd][r] + bv;
            }
        }
    }
}

// ---------------------------------------------------------------------------
// K3: sampled scores, M = max - mean, stable top-30 by rank count
//  (unchanged from R2, passing).
// ---------------------------------------------------------------------------
__global__ __launch_bounds__(256) void topk_kernel(
    const float* __restrict__ q_h, const float* __restrict__ k_h,
    const int* __restrict__ idxs, int* __restrict__ sel)
{
    __shared__ float ks[S_ * 20];
    __shared__ float Marr[S_];
    __shared__ int cnt;
    int bh  = blockIdx.x;
    int tid = threadIdx.x;
    if (tid == 0) cnt = 0;

    const float* kp = k_h + (size_t)bh * S_ * DK_;
    for (int idx = tid; idx < S_ * DK_; idx += 256)
        ks[(idx >> 4) * 20 + (idx & 15)] = kp[idx];
    __syncthreads();

    float qr[16];
    const float4* qp = (const float4*)(q_h + ((size_t)bh * S_ + tid) * DK_);
#pragma unroll
    for (int i = 0; i < 4; i++) {
        float4 t4 = qp[i];
        qr[4*i] = t4.x; qr[4*i+1] = t4.y; qr[4*i+2] = t4.z; qr[4*i+3] = t4.w;
    }
    int idxr[SK_];
    const int* ip = idxs + tid * SK_;
#pragma unroll
    for (int s = 0; s < SK_; s++) idxr[s] = ip[s];

    float mx = -1e30f, sm = 0.f;
#pragma unroll
    for (int s = 0; s < SK_; s++) {
        const float4* kr = (const float4*)(ks + idxr[s] * 20);
        float4 k0 = kr[0], k1 = kr[1], k2 = kr[2], k3 = kr[3];
        float d0 = qr[0]*k0.x, d1 = qr[1]*k0.y, d2 = qr[2]*k0.z, d3 = qr[3]*k0.w;
        d0 = fmaf(qr[4],  k1.x, d0); d1 = fmaf(qr[5],  k1.y, d1);
        d2 = fmaf(qr[6],  k1.z, d2); d3 = fmaf(qr[7],  k1.w, d3);
        d0 = fmaf(qr[8],  k2.x, d0); d1 = fmaf(qr[9],  k2.y, d1);
        d2 = fmaf(qr[10], k2.z, d2); d3 = fmaf(qr[11], k2.w, d3);
        d0 = fmaf(qr[12], k3.x, d0); d1 = fmaf(qr[13], k3.y, d1);
        d2 = fmaf(qr[14], k3.z, d2); d3 = fmaf(qr[15], k3.w, d3);
        float dot = (d0 + d1) + (d2 + d3);
        mx = fmaxf(mx, dot);
        sm += dot;
    }
    float M = mx - sm * (1.0f / 30.0f);
    Marr[tid] = M;
    __syncthreads();

    int higher = 0;
    for (int j = 0; j < S_; j++) {
        float Mj = Marr[j];
        if (Mj > M || (Mj == M && j < tid)) higher++;
    }
    if (higher < NT_) {
        int slot = atomicAdd(&cnt, 1);
        sel[bh * NT_ + slot] = tid;
    }
}

// ---------------------------------------------------------------------------
// K4: attention + context assembly.  Same structure as R2 but ctx is written
//  as bf16 hi/lo pair (feeds the MFMA linear directly; same byte traffic).
// ---------------------------------------------------------------------------
__global__ __launch_bounds__(256) void attn_kernel(
    const float* __restrict__ q_h, const float* __restrict__ k_h,
    const float* __restrict__ v_h, const int* __restrict__ sel,
    ushort* __restrict__ ctx_hi, ushort* __restrict__ ctx_lo)
{
    __shared__ float ks[S_ * 20];
    __shared__ float vs[S_ * 20];
    __shared__ float P[NT_][S_ + 1];
    __shared__ float qs[NT_][16];
    __shared__ float partial[16][17];
    __shared__ float vmean_s[16];
    __shared__ int sel_s[NT_];
    __shared__ int selflag[S_];

    int bh = blockIdx.x, b = bh >> 3, h = bh & 7;
    int tid = threadIdx.x;

    const float* kp = k_h + (size_t)bh * S_ * DK_;
    const float* vp = v_h + (size_t)bh * S_ * DK_;
    for (int idx = tid; idx < S_ * DK_; idx += 256) {
        int r = idx >> 4, c = idx & 15;
        ks[r * 20 + c] = kp[idx];
        vs[r * 20 + c] = vp[idx];
    }
    selflag[tid] = 0;
    if (tid < NT_) sel_s[tid] = sel[bh * NT_ + tid];
    __syncthreads();
    if (tid < NT_) selflag[sel_s[tid]] = 1;
    for (int idx = tid; idx < NT_ * 16; idx += 256) {
        int u = idx >> 4, c = idx & 15;
        qs[u][c] = q_h[((size_t)bh * S_ + sel_s[u]) * DK_ + c];
    }
    {
        int dk = tid & 15, chunk = tid >> 4;
        float s = 0.f;
#pragma unroll
        for (int r = 0; r < 16; r++) s += vs[(chunk * 16 + r) * 20 + dk];
        partial[chunk][dk] = s;
    }
    __syncthreads();
    if (tid < 16) {
        float s = 0.f;
#pragma unroll
        for (int c = 0; c < 16; c++) s += partial[c][tid];
        vmean_s[tid] = s * (1.0f / 256.0f);
    }
    __syncthreads();

    // baseline rows (non-selected): bf16 hi/lo of vmean
    if (!selflag[tid]) {
        alignas(16) ushort hh[16], ll[16];
#pragma unroll
        for (int i = 0; i < 16; i++) {
            float v = vmean_s[i];
            ushort hb = bf16_rne(v);
            hh[i] = hb;
            ll[i] = bf16_rne(v - bf16_to_f(hb));
        }
        size_t off = ((size_t)(b * S_ + tid)) * D_ + h * DK_;
        ((uint4*)(ctx_hi + off))[0] = ((uint4*)hh)[0];
        ((uint4*)(ctx_hi + off))[1] = ((uint4*)hh)[1];
        ((uint4*)(ctx_lo + off))[0] = ((uint4*)ll)[0];
        ((uint4*)(ctx_lo + off))[1] = ((uint4*)ll)[1];
    }

    // scores + softmax + PV: group g (8 threads) owns selected row g
    int g = tid >> 3, j = tid & 7;
    if (g < NT_) {
        float qreg[16];
        const float4* q4 = (const float4*)qs[g];
#pragma unroll
        for (int i = 0; i < 4; i++) {
            float4 t4 = q4[i];
            qreg[4*i] = t4.x; qreg[4*i+1] = t4.y; qreg[4*i+2] = t4.z; qreg[4*i+3] = t4.w;
        }
        float sc[32];
        float mx = -1e30f;
#pragma unroll
        for (int li = 0; li < 32; li++) {
            int l = j + li * 8;
            const float4* kr = (const float4*)(ks + l * 20);
            float4 k0 = kr[0], k1 = kr[1], k2 = kr[2], k3 = kr[3];
            float d0 = qreg[0]*k0.x, d1 = qreg[1]*k0.y, d2 = qreg[2]*k0.z, d3 = qreg[3]*k0.w;
            d0 = fmaf(qreg[4],  k1.x, d0); d1 = fmaf(qreg[5],  k1.y, d1);
            d2 = fmaf(qreg[6],  k1.z, d2); d3 = fmaf(qreg[7],  k1.w, d3);
            d0 = fmaf(qreg[8],  k2.x, d0); d1 = fmaf(qreg[9],  k2.y, d1);
            d2 = fmaf(qreg[10], k2.z, d2); d3 = fmaf(qreg[11], k2.w, d3);
            d0 = fmaf(qreg[12], k3.x, d0); d1 = fmaf(qreg[13], k3.y, d1);
            d2 = fmaf(qreg[14], k3.z, d2); d3 = fmaf(qreg[15], k3.w, d3);
            sc[li] = ((d0 + d1) + (d2 + d3)) * 0.25f;
            mx = fmaxf(mx, sc[li]);
        }
        mx = fmaxf(mx, __shfl_xor(mx, 1));
        mx = fmaxf(mx, __shfl_xor(mx, 2));
        mx = fmaxf(mx, __shfl_xor(mx, 4));
        float se = 0.f;
#pragma unroll
        for (int li = 0; li < 32; li++) {
            float e = __expf(sc[li] - mx);
            P[g][j + li * 8] = e;
            se += e;
        }
        se += __shfl_xor(se, 1);
        se += __shfl_xor(se, 2);
        se += __shfl_xor(se, 4);
        float inv = 1.0f / se;

        int dk0 = j * 2;
        float o0 = 0.f, o1 = 0.f;
#pragma unroll 8
        for (int l = 0; l < S_; l++) {
            float p = P[g][l];
            float2 vv = *(const float2*)(vs + l * 20 + dk0);
            o0 = fmaf(p, vv.x, o0);
            o1 = fmaf(p, vv.y, o1);
        }
        int lrow = sel_s[g];
        float v0 = o0 * inv, v1 = o1 * inv;
        ushort h0 = bf16_rne(v0), h1 = bf16_rne(v1);
        ushort l0 = bf16_rne(v0 - bf16_to_f(h0));
        ushort l1 = bf16_rne(v1 - bf16_to_f(h1));
        size_t off = ((size_t)(b * S_ + lrow)) * D_ + h * DK_ + dk0;
        *(uint*)(ctx_hi + off) = (uint)h0 | ((uint)h1 << 16);
        *(uint*)(ctx_lo + off) = (uint)l0 | ((uint)l1 << 16);
    }
}

// ---------------------------------------------------------------------------
// K5: final linear as MFMA GEMM.  M=32768 rows, N=128, K=128.
//  Block = 128 rows; wave = 32 rows x 128 cols (2 m-frags x 8 n-frags).
//  A (ctx hi/lo) staged in LDS, pad-136 rows (272 B stride -> 2-way banks =
//  free); B (lin_w hi/lo) 16B contiguous loads from L1/L2.  3-product hi/lo.
// ---------------------------------------------------------------------------
__global__ __launch_bounds__(256) void linear_mfma_kernel(
    const ushort* __restrict__ ctx_hi, const ushort* __restrict__ ctx_lo,
    const ushort* __restrict__ w_hi, const ushort* __restrict__ w_lo,
    const float* __restrict__ bias, float* __restrict__ out)
{
    __shared__ ushort ahi[128 * 136];
    __shared__ ushort alo[128 * 136];

    int tid  = threadIdx.x;
    int lane = tid & 63, wid = tid >> 6;
    int lm = lane & 15, kb = lane >> 4;
    size_t rowbase = (size_t)blockIdx.x * 128;

    // stage A tile: 128 rows x 128 c, hi+lo (16B per thread-iteration each)
    for (int idx = tid; idx < 2048; idx += 256) {
        int row = idx >> 4, c16 = idx & 15;
        short8 vh = *(const short8*)(ctx_hi + (rowbase + row) * 128 + c16 * 8);
        short8 vl = *(const short8*)(ctx_lo + (rowbase + row) * 128 + c16 * 8);
        *(short8*)(ahi + row * 136 + c16 * 8) = vh;
        *(short8*)(alo + row * 136 + c16 * 8) = vl;
    }
    __syncthreads();

    floatx4 acc[16];   // [mf][nf] -> acc[mf*8+nf]
#pragma unroll
    for (int i = 0; i < 16; i++) acc[i] = (floatx4){0.f, 0.f, 0.f, 0.f};

    const ushort* arow_h = ahi + (wid * 32 + lm) * 136 + kb * 8;
    const ushort* arow_l = alo + (wid * 32 + lm) * 136 + kb * 8;

#pragma unroll
    for (int kstep = 0; kstep < 4; kstep++) {
        short8 afh[2], afl[2];
#pragma unroll
        for (int mf = 0; mf < 2; mf++) {
            afh[mf] = *(const short8*)(arow_h + mf * 16 * 136 + kstep * 32);
            afl[mf] = *(const short8*)(arow_l + mf * 16 * 136 + kstep * 32);
        }
        short8 bfh[8], bfl[8];
#pragma unroll
        for (int nf = 0; nf < 8; nf++) {
            const ushort* wp = w_hi + (size_t)(nf * 16 + lm) * 128 + kstep * 32 + kb * 8;
            const ushort* wq = w_lo + (size_t)(nf * 16 + lm) * 128 + kstep * 32 + kb * 8;
            bfh[nf] = *(const short8*)wp;
            bfl[nf] = *(const short8*)wq;
        }
#pragma unroll
        for (int mf = 0; mf < 2; mf++) {
#pragma unroll
            for (int nf = 0; nf < 8; nf++) {
                int a = mf * 8 + nf;
                acc[a] = __builtin_amdgcn_mfma_f32_16x16x32_bf16(afh[mf], bfh[nf], acc[a], 0, 0, 0);
                acc[a] = __builtin_amdgcn_mfma_f32_16x16x32_bf16(afl[mf], bfh[nf], acc[a], 0, 0, 0);
                acc[a] = __builtin_amdgcn_mfma_f32_16x16x32_bf16(afh[mf], bfl[nf], acc[a], 0, 0, 0);
            }
        }
    }

#pragma unroll
    for (int nf = 0; nf < 8; nf++) {
        int col = nf * 16 + lm;
        float bv = bias[col];
#pragma unroll
        for (int mf = 0; mf < 2; mf++) {
#pragma unroll
            for (int r = 0; r < 4; r++) {
                int row = wid * 32 + mf * 16 + kb * 4 + r;
                out[(rowbase + row) * 128 + col] = acc[mf * 8 + nf][r] + bv;
            }
        }
    }
}

// ---------------------------------------------------------------------------
extern "C" void kernel_launch(void* const* d_in, const int* in_sizes, int n_in,
                              void* d_out, int out_size, void* d_ws, size_t ws_size,
                              hipStream_t stream)
{
    const float* query = (const float*)d_in[0];
    const float* key   = (const float*)d_in[1];
    const float* value = (const float*)d_in[2];
    const float* ckw   = (const float*)d_in[3];
    const float* ckb   = (const float*)d_in[4];
    const float* cvw   = (const float*)d_in[5];
    const float* cvb   = (const float*)d_in[6];
    const float* lw    = (const float*)d_in[7];
    const float* lb    = (const float*)d_in[8];
    const int*   isamp = (const int*)d_in[9];
    float* out = (float*)d_out;
    float* ws  = (float*)d_ws;

    const size_t NBSD = (size_t)B_ * S_ * D_;   // 4,194,304 floats
    float* q_h  = ws;                   // (B,H,S,DK)
    float* kbuf = ws + NBSD;            // k_rot (B,S,D); overlaid by ctx hi/lo
    float* k_h  = ws + 2 * NBSD;        // (B,H,S,DK)
    float* v_h  = ws + 3 * NBSD;        // (B,H,S,DK)
    int*   sel  = (int*)(ws + 4 * NBSD);        // (B*H, 30)
    ushort* wk_hi = (ushort*)(sel + B_ * H_ * NT_);   // [7][256][256] bf16 each
    ushort* wk_lo = wk_hi + 7 * 65536;
    ushort* wv_hi = wk_lo + 7 * 65536;
    ushort* lw_hi = wv_hi + 7 * 65536;  // [128][128]
    ushort* lw_lo = lw_hi + 16384;
    float*  trig  = (float*)(lw_lo + 16384);    // [256][64][2]
    // ctx hi/lo overlay kbuf (free after conv<true>)
    ushort* ctx_hi = (ushort*)kbuf;
    ushort* ctx_lo = ctx_hi + NBSD;

    wprep_kernel<<<dim3(576), 256, 0, stream>>>(ckw, cvw, lw, wk_hi, wk_lo, wv_hi, lw_hi, lw_lo);
    trig_kernel<<<dim3(64), 256, 0, stream>>>(trig);
    rotary_kernel<<<dim3((B_ * S_ * 64) / 256), 256, 0, stream>>>(query, key, trig, q_h, kbuf);
    conv_mfma_kernel<true ><<<dim3(B_, 4), 256, 0, stream>>>(kbuf,  wk_hi, wk_lo, ckb, k_h);
    conv_mfma_kernel<false><<<dim3(B_, 4), 256, 0, stream>>>(value, wv_hi, wv_hi, cvb, v_h);
    topk_kernel<<<dim3(B_ * H_), 256, 0, stream>>>(q_h, k_h, isamp, sel);
    attn_kernel<<<dim3(B_ * H_), 256, 0, stream>>>(q_h, k_h, v_h, sel, ctx_hi, ctx_lo);
    linear_mfma_kernel<<<dim3(256), 256, 0, stream>>>(ctx_hi, ctx_lo, lw_hi, lw_lo, lb, out);
}